// Round 2
// baseline (3217.641 us; speedup 1.0000x reference)
//
#include <hip/hip_runtime.h>

// GraphSAGE 2-layer, N=100000, E=1600000, F=128. ALL float tensors are
// float32 (round-1 NaN proved the bf16 reading was wrong); src/dst int32.
//
// Pipeline:
//   memset(deg+s)
//   scatter1: s[dst] += w_e * in_feat[src]  (f32 atomics; also counts deg)
//   gemm1:    d_out = relu(in_feat@Ws1^T + b1 + (s/deg)@Wn1^T)   [h1 in d_out]
//   memset(s)
//   scatter2: s[dst] += w_e * h1[src]       (h1 read from d_out)
//   gemm2:    d_out = h1@Ws2^T + b2 + (s/deg)@Wn2^T   [in-place: each block
//             stages its own 16 rows to LDS before overwriting them]

#define NN 100000
#define NE 1600000
#define F 128

static const size_t S_OFF = 524288;  // bytes; deg f32[NN] lives at offset 0

// one wave per edge; lane l handles features 2l, 2l+1
__global__ __launch_bounds__(256) void scatter_kernel(
    const float* __restrict__ h,    // f32 [NN, F]
    const float* __restrict__ w,    // f32 [NE]
    const int* __restrict__ src,
    const int* __restrict__ dst,
    float* __restrict__ s,          // f32 [NN, F]
    float* __restrict__ deg,        // f32 [NN]
    int add_deg)
{
    int e = blockIdx.x * 4 + (threadIdx.x >> 6);   // NE divisible by 4
    int lane = threadIdx.x & 63;
    int sn = src[e];
    int dn = dst[e];
    float wf = w[e];
    float2 p = *(const float2*)(h + (size_t)sn * F + lane * 2);
    float* sp = s + (size_t)dn * F + lane * 2;
    unsafeAtomicAdd(sp,     wf * p.x);
    unsafeAtomicAdd(sp + 1, wf * p.y);
    if (add_deg && lane == 0) unsafeAtomicAdd(&deg[dn], 1.0f);
}

// 16 nodes/block, 256 threads: j = t&127 (output feature), g = t>>7,
// thread accumulates 8 nodes. Pass A: h@Ws^T from LDS (broadcast reads);
// pass B: (s/deg)@Wn^T. Weight rows stream from global (L2-resident,
// reused by all 6250 blocks). NOTE: h and out may alias (in-place layer 2):
// each block reads only rows [16b,16b+16) and writes only those rows, and
// all global reads of h happen before the first __syncthreads().
__global__ __launch_bounds__(256) void sage_gemm(
    const float* h,                          // f32 [NN, F] (may alias out)
    const float* __restrict__ s,             // f32 [NN, F]
    const float* __restrict__ deg,           // f32 [NN]
    const float* __restrict__ Ws,            // f32 [F, F]
    const float* __restrict__ bias,          // f32 [F]
    const float* __restrict__ Wn,            // f32 [F, F]
    float* out,                              // f32 [NN, F]
    int relu)
{
    __shared__ float xs[16][F];
    __shared__ float invd[16];

    int t = threadIdx.x;
    int j = t & 127;
    int g = t >> 7;
    int base = blockIdx.x * 16;

    // stage h rows: 16*128 f32, float4 chunks
    for (int idx = t; idx < 16 * 32; idx += 256) {
        int n = idx >> 5, kq = idx & 31;
        *(float4*)&xs[n][kq * 4] = *(const float4*)(h + (size_t)(base + n) * F + kq * 4);
    }
    if (t < 16) invd[t] = 1.0f / fmaxf(deg[base + t], 1.0f);
    __syncthreads();

    float acc[8];
#pragma unroll
    for (int i = 0; i < 8; i++) acc[i] = 0.0f;

    // ---- pass A: h @ Ws^T ----
    for (int kc = 0; kc < F; kc += 4) {
        float4 wv = *(const float4*)(Ws + j * F + kc);
#pragma unroll
        for (int i = 0; i < 8; i++) {
            const float* xr = &xs[g * 8 + i][kc];
            acc[i] += xr[0] * wv.x + xr[1] * wv.y + xr[2] * wv.z + xr[3] * wv.w;
        }
    }
    __syncthreads();

    // restage with neigh = s/deg
    for (int idx = t; idx < 16 * 32; idx += 256) {
        int n = idx >> 5, kq = idx & 31;
        float4 sv = *(const float4*)(s + (size_t)(base + n) * F + kq * 4);
        float iv = invd[n];
        xs[n][kq * 4]     = sv.x * iv;
        xs[n][kq * 4 + 1] = sv.y * iv;
        xs[n][kq * 4 + 2] = sv.z * iv;
        xs[n][kq * 4 + 3] = sv.w * iv;
    }
    __syncthreads();

    // ---- pass B: neigh @ Wn^T ----
    for (int kc = 0; kc < F; kc += 4) {
        float4 wv = *(const float4*)(Wn + j * F + kc);
#pragma unroll
        for (int i = 0; i < 8; i++) {
            const float* xr = &xs[g * 8 + i][kc];
            acc[i] += xr[0] * wv.x + xr[1] * wv.y + xr[2] * wv.z + xr[3] * wv.w;
        }
    }

    float bj = bias[j];
#pragma unroll
    for (int i = 0; i < 8; i++) {
        int n = base + g * 8 + i;
        float v = acc[i] + bj;
        if (relu) v = fmaxf(v, 0.0f);
        out[(size_t)n * F + j] = v;
    }
}

extern "C" void kernel_launch(void* const* d_in, const int* in_sizes, int n_in,
                              void* d_out, int out_size, void* d_ws, size_t ws_size,
                              hipStream_t stream) {
    const float* in_feat = (const float*)d_in[0];
    const float* weights = (const float*)d_in[1];
    const int* src = (const int*)d_in[2];
    const int* dst = (const int*)d_in[3];
    const float* Ws1 = (const float*)d_in[4];
    const float* b1  = (const float*)d_in[5];
    const float* Wn1 = (const float*)d_in[6];
    const float* Ws2 = (const float*)d_in[7];
    const float* b2  = (const float*)d_in[8];
    const float* Wn2 = (const float*)d_in[9];

    float* deg = (float*)d_ws;
    float* s   = (float*)((char*)d_ws + S_OFF);
    float* out = (float*)d_out;

    // zero deg + s
    hipMemsetAsync(d_ws, 0, S_OFF + (size_t)NN * F * 4, stream);

    // ---- layer 1 ----
    scatter_kernel<<<NE / 4, 256, 0, stream>>>(in_feat, weights, src, dst, s, deg, 1);
    sage_gemm<<<NN / 16, 256, 0, stream>>>(in_feat, s, deg, Ws1, b1, Wn1, out, 1);

    // ---- layer 2 ----
    hipMemsetAsync(s, 0, (size_t)NN * F * 4, stream);
    scatter_kernel<<<NE / 4, 256, 0, stream>>>(out, weights, src, dst, s, deg, 0);
    sage_gemm<<<NN / 16, 256, 0, stream>>>(out, s, deg, Ws2, b2, Wn2, out, 0);
}

// Round 4
// 1061.899 us; speedup vs baseline: 3.0301x; 3.0301x over previous
//
#include <hip/hip_runtime.h>

// GraphSAGE 2-layer, N=100000, E=1600000, F=128, all f32.
//
// Main path (ws >= ~65 MB; round-3 crash confirmed the CSR branch runs):
//   memset(cnt+fill)
//   count:   cnt[dst[e]]++                         (int atomics)
//   scan1/2/3: row = exclusive_scan(cnt)           (dedicated bsum buffer!)
//   fill:    csr_src/csr_w bucketed by dst         (int cursor atomics)
//   gather1: s[n] = (1/deg_n) * sum_e w_e*in_feat[src_e]   (plain stores)
//   gemm1:   d_out = relu(in_feat@Ws1^T + b1 + s@Wn1^T)
//   gather2: s[n] = (1/deg_n) * sum_e w_e*h1[src_e]        (h1 = d_out)
//   gemm2:   d_out = h1@Ws2^T + b2 + s@Wn2^T   (in-place: each block stages
//            its own 16 rows to LDS before overwriting them — disjoint rows)
//
// Round-3 post-mortem: scan1's block sums were routed into `fill` while
// scan2/3 read them from poisoned `csrc` -> negative row offsets -> OOB
// stores -> abort. Fixed with a dedicated BSUM region.

#define NN 100000
#define NE 1600000
#define F 128

#define SCAN_BS 1024
#define NBLK ((NN + SCAN_BS - 1) / SCAN_BS)   // 98

// ---- main-path ws layout (bytes) ----
static const size_t CNT_OFF   = 0;          // int[NN]    400,000
static const size_t FILL_OFF  = 400000;     // int[NN]    400,000
static const size_t ROW_OFF   = 800000;     // int[NN]    400,000
static const size_t BSUM_OFF  = 1200000;    // int[NBLK]  (4 KB slot)
static const size_t CSRC_OFF  = 1204096;    // int[NE]  6,400,000
static const size_t CSRW_OFF  = 7604096;    // f32[NE]  6,400,000
static const size_t SMAIN_OFF = 14004096;   // f32[NN*F] 51,200,000
static const size_t WS_MAIN_NEED = 65204096;

// ---- fallback ws layout ----
static const size_t S_OFF = 524288;         // deg f32[NN] @0, s f32[NN*F] @S_OFF

// ======================= CSR build =======================

__global__ __launch_bounds__(256) void count_kernel(const int* __restrict__ dst,
                                                    int* __restrict__ cnt) {
    int e = blockIdx.x * 256 + threadIdx.x;
    if (e < NE) atomicAdd(&cnt[dst[e]], 1);
}

// per-1024-chunk exclusive scan; chunk totals -> bsum
__global__ __launch_bounds__(256) void scan1_kernel(const int* __restrict__ cnt,
                                                    int* __restrict__ part,
                                                    int* __restrict__ bsum) {
    __shared__ int ts[256];
    int t = threadIdx.x;
    int base = blockIdx.x * SCAN_BS + t * 4;
    int c0 = (base     < NN) ? cnt[base]     : 0;
    int c1 = (base + 1 < NN) ? cnt[base + 1] : 0;
    int c2 = (base + 2 < NN) ? cnt[base + 2] : 0;
    int c3 = (base + 3 < NN) ? cnt[base + 3] : 0;
    int sum = c0 + c1 + c2 + c3;
    ts[t] = sum;
    __syncthreads();
    for (int off = 1; off < 256; off <<= 1) {
        int u = (t >= off) ? ts[t - off] : 0;
        __syncthreads();
        ts[t] += u;
        __syncthreads();
    }
    int excl = ts[t] - sum;
    if (t == 255) bsum[blockIdx.x] = ts[255];
    if (base     < NN) part[base]     = excl;
    if (base + 1 < NN) part[base + 1] = excl + c0;
    if (base + 2 < NN) part[base + 2] = excl + c0 + c1;
    if (base + 3 < NN) part[base + 3] = excl + c0 + c1 + c2;
}

__global__ void scan2_kernel(int* __restrict__ bsum) {
    if (threadIdx.x == 0 && blockIdx.x == 0) {
        int acc = 0;
        for (int i = 0; i < NBLK; i++) { int v = bsum[i]; bsum[i] = acc; acc += v; }
    }
}

__global__ __launch_bounds__(256) void scan3_kernel(int* __restrict__ part,
                                                    const int* __restrict__ bsum) {
    int i = blockIdx.x * 256 + threadIdx.x;
    if (i < NN) part[i] += bsum[i / SCAN_BS];
}

__global__ __launch_bounds__(256) void fill_kernel(const int* __restrict__ src,
                                                   const int* __restrict__ dst,
                                                   const float* __restrict__ w,
                                                   const int* __restrict__ row_start,
                                                   int* __restrict__ fill_cnt,
                                                   int* __restrict__ csrc,
                                                   float* __restrict__ csrw) {
    int e = blockIdx.x * 256 + threadIdx.x;
    if (e >= NE) return;
    int d = dst[e];
    int pos = row_start[d] + atomicAdd(&fill_cnt[d], 1);
    csrc[pos] = src[e];
    csrw[pos] = w[e];
}

// ======================= gather (atomic-free aggregation) =======================
// 2 nodes per 256-block; 128 threads per node, thread j owns feature j.
__global__ __launch_bounds__(256) void gather_kernel(const float* __restrict__ h,
                                                     const int* __restrict__ row_start,
                                                     const int* __restrict__ cnt,
                                                     const int* __restrict__ csrc,
                                                     const float* __restrict__ csrw,
                                                     float* __restrict__ s) {
    int t = threadIdx.x;
    int j = t & 127;
    int n = blockIdx.x * 2 + (t >> 7);
    if (n >= NN) return;
    int beg = row_start[n];
    int m = cnt[n];
    float acc = 0.0f;
    int e = 0;
    for (; e + 1 < m; e += 2) {
        int s0 = csrc[beg + e], s1 = csrc[beg + e + 1];
        float w0 = csrw[beg + e], w1 = csrw[beg + e + 1];
        acc += w0 * h[(size_t)s0 * F + j] + w1 * h[(size_t)s1 * F + j];
    }
    if (e < m) acc += csrw[beg + e] * h[(size_t)csrc[beg + e] * F + j];
    float invd = 1.0f / fmaxf((float)m, 1.0f);
    s[(size_t)n * F + j] = acc * invd;
}

// ======================= fallback: atomic scatter =======================

__global__ __launch_bounds__(256) void scatter_kernel(const float* __restrict__ h,
                                                      const float* __restrict__ w,
                                                      const int* __restrict__ src,
                                                      const int* __restrict__ dst,
                                                      float* __restrict__ s,
                                                      float* __restrict__ deg,
                                                      int add_deg) {
    int e = blockIdx.x * 4 + (threadIdx.x >> 6);
    int lane = threadIdx.x & 63;
    int sn = src[e];
    int dn = dst[e];
    float wf = w[e];
    float2 p = *(const float2*)(h + (size_t)sn * F + lane * 2);
    float* sp = s + (size_t)dn * F + lane * 2;
    unsafeAtomicAdd(sp,     wf * p.x);
    unsafeAtomicAdd(sp + 1, wf * p.y);
    if (add_deg && lane == 0) unsafeAtomicAdd(&deg[dn], 1.0f);
}

// ======================= GEMM =======================
// 16 nodes/block; j = t&127 output feature, g = t>>7, 8 nodes per thread.
// deg == nullptr -> s is already normalized. h may alias out (in-place):
// blocks read only their own 16 rows, before the first __syncthreads().
__global__ __launch_bounds__(256) void sage_gemm(const float* h,
                                                 const float* __restrict__ s,
                                                 const float* deg,   // nullable
                                                 const float* __restrict__ Ws,
                                                 const float* __restrict__ bias,
                                                 const float* __restrict__ Wn,
                                                 float* out,
                                                 int relu) {
    __shared__ float xs[16][F];
    __shared__ float invd[16];

    int t = threadIdx.x;
    int j = t & 127;
    int g = t >> 7;
    int base = blockIdx.x * 16;

    for (int idx = t; idx < 16 * 32; idx += 256) {
        int n = idx >> 5, kq = idx & 31;
        *(float4*)&xs[n][kq * 4] = *(const float4*)(h + (size_t)(base + n) * F + kq * 4);
    }
    if (t < 16) invd[t] = deg ? 1.0f / fmaxf(deg[base + t], 1.0f) : 1.0f;
    __syncthreads();

    float acc[8];
#pragma unroll
    for (int i = 0; i < 8; i++) acc[i] = 0.0f;

    for (int kc = 0; kc < F; kc += 4) {
        float4 wv = *(const float4*)(Ws + j * F + kc);
#pragma unroll
        for (int i = 0; i < 8; i++) {
            const float* xr = &xs[g * 8 + i][kc];
            acc[i] += xr[0] * wv.x + xr[1] * wv.y + xr[2] * wv.z + xr[3] * wv.w;
        }
    }
    __syncthreads();

    for (int idx = t; idx < 16 * 32; idx += 256) {
        int n = idx >> 5, kq = idx & 31;
        float4 sv = *(const float4*)(s + (size_t)(base + n) * F + kq * 4);
        float iv = invd[n];
        xs[n][kq * 4]     = sv.x * iv;
        xs[n][kq * 4 + 1] = sv.y * iv;
        xs[n][kq * 4 + 2] = sv.z * iv;
        xs[n][kq * 4 + 3] = sv.w * iv;
    }
    __syncthreads();

    for (int kc = 0; kc < F; kc += 4) {
        float4 wv = *(const float4*)(Wn + j * F + kc);
#pragma unroll
        for (int i = 0; i < 8; i++) {
            const float* xr = &xs[g * 8 + i][kc];
            acc[i] += xr[0] * wv.x + xr[1] * wv.y + xr[2] * wv.z + xr[3] * wv.w;
        }
    }

    float bj = bias[j];
#pragma unroll
    for (int i = 0; i < 8; i++) {
        int n = base + g * 8 + i;
        float v = acc[i] + bj;
        if (relu) v = fmaxf(v, 0.0f);
        out[(size_t)n * F + j] = v;
    }
}

extern "C" void kernel_launch(void* const* d_in, const int* in_sizes, int n_in,
                              void* d_out, int out_size, void* d_ws, size_t ws_size,
                              hipStream_t stream) {
    const float* in_feat = (const float*)d_in[0];
    const float* weights = (const float*)d_in[1];
    const int* src = (const int*)d_in[2];
    const int* dst = (const int*)d_in[3];
    const float* Ws1 = (const float*)d_in[4];
    const float* b1  = (const float*)d_in[5];
    const float* Wn1 = (const float*)d_in[6];
    const float* Ws2 = (const float*)d_in[7];
    const float* b2  = (const float*)d_in[8];
    const float* Wn2 = (const float*)d_in[9];
    float* out = (float*)d_out;

    if (ws_size >= WS_MAIN_NEED) {
        // ---- CSR path ----
        int* cnt   = (int*)((char*)d_ws + CNT_OFF);
        int* fill  = (int*)((char*)d_ws + FILL_OFF);
        int* row   = (int*)((char*)d_ws + ROW_OFF);
        int* bsum  = (int*)((char*)d_ws + BSUM_OFF);
        int* csrc  = (int*)((char*)d_ws + CSRC_OFF);
        float* csrw = (float*)((char*)d_ws + CSRW_OFF);
        float* s   = (float*)((char*)d_ws + SMAIN_OFF);

        hipMemsetAsync(d_ws, 0, 800000, stream);  // cnt + fill
        count_kernel<<<(NE + 255) / 256, 256, 0, stream>>>(dst, cnt);
        scan1_kernel<<<NBLK, 256, 0, stream>>>(cnt, row, bsum);
        scan2_kernel<<<1, 64, 0, stream>>>(bsum);
        scan3_kernel<<<(NN + 255) / 256, 256, 0, stream>>>(row, bsum);
        fill_kernel<<<(NE + 255) / 256, 256, 0, stream>>>(src, dst, weights, row, fill, csrc, csrw);

        // layer 1
        gather_kernel<<<NN / 2, 256, 0, stream>>>(in_feat, row, cnt, csrc, csrw, s);
        sage_gemm<<<NN / 16, 256, 0, stream>>>(in_feat, s, nullptr, Ws1, b1, Wn1, out, 1);
        // layer 2
        gather_kernel<<<NN / 2, 256, 0, stream>>>(out, row, cnt, csrc, csrw, s);
        sage_gemm<<<NN / 16, 256, 0, stream>>>(out, s, nullptr, Ws2, b2, Wn2, out, 0);
    } else {
        // ---- fallback: round-2 atomic scatter path ----
        float* deg = (float*)d_ws;
        float* s   = (float*)((char*)d_ws + S_OFF);
        hipMemsetAsync(d_ws, 0, S_OFF + (size_t)NN * F * 4, stream);
        scatter_kernel<<<NE / 4, 256, 0, stream>>>(in_feat, weights, src, dst, s, deg, 1);
        sage_gemm<<<NN / 16, 256, 0, stream>>>(in_feat, s, deg, Ws1, b1, Wn1, out, 1);
        hipMemsetAsync(s, 0, (size_t)NN * F * 4, stream);
        scatter_kernel<<<NE / 4, 256, 0, stream>>>(out, weights, src, dst, s, deg, 0);
        sage_gemm<<<NN / 16, 256, 0, stream>>>(out, s, deg, Ws2, b2, Wn2, out, 0);
    }
}

// Round 5
// 767.996 us; speedup vs baseline: 4.1897x; 1.3827x over previous
//
#include <hip/hip_runtime.h>

// GraphSAGE 2-layer, N=100000, E=1600000, F=128. Inputs f32; src/dst int32.
//
// CSR path (ws >= ~65 MB, proven in rounds 3/4):
//   memset(cnt); count; scan1/2/3 -> row[NN+1]; cursor=row copy; fill CSR
//   wprep: Wcat_l[n][k] bf16, k<128 = Ws_l[n][k], k>=128 = Wn_l[n][k-128]
//   gather1: s_bf[n] = bf16( (1/deg) sum w_e * in_feat[src_e] )   (f32 reads)
//   gemm1  : h1_bf = bf16(relu(in_feat@Ws1^T + b1 + s@Wn1^T))     (MFMA bf16)
//   gather2: s_bf[n] = bf16( (1/deg) sum w_e * h1[src_e] )        (bf16 reads)
//   gemm2  : d_out = f32(h1@Ws2^T + b2 + s@Wn2^T)                 (MFMA bf16)
//
// MFMA 16x16x32_bf16 facts used (m89/m120-verified):
//   A-frag: lane l holds A[m=l&15][k=(l>>4)*8+j], j=0..7 (8 bf16)
//   B-frag: lane l holds B[k=(l>>4)*8+j][n=l&15]  -> = W[n][k] row-major
//   C/D   : lane l, reg r -> col=l&15, row=(l>>4)*4+r

#define NN 100000
#define NE 1600000
#define F 128

#define SCAN_BS 1024
#define NBLK ((NN + SCAN_BS - 1) / SCAN_BS)   // 98

// ---- ws layout (bytes) ----
static const size_t CNT_OFF   = 0;          // int[NN] counters, later fill cursor
static const size_t ROW_OFF   = 400000;     // int[NN+1]
static const size_t BSUM_OFF  = 800016;     // int[NBLK]
static const size_t CSRC_OFF  = 804112;     // int[NE]
static const size_t CSRW_OFF  = 7204112;    // f32[NE]
static const size_t WCAT1_OFF = 13604112;   // bf16[128*256]
static const size_t WCAT2_OFF = 13669648;   // bf16[128*256]
static const size_t SBF_OFF   = 13735184;   // bf16[NN*F]
static const size_t H1BF_OFF  = 39335184;   // bf16[NN*F]
static const size_t WS_NEED   = 64935184;

// ---- fallback (round-4 f32 path) layout ----
static const size_t FB_S_OFF = 524288;      // deg f32[NN] @0, s f32[NN*F]

typedef __attribute__((ext_vector_type(8))) short short8;
typedef __attribute__((ext_vector_type(4))) float float4v;

__device__ __forceinline__ float bf2f(unsigned int u16) {
    unsigned int x = u16 << 16;
    float f;
    __builtin_memcpy(&f, &x, 4);
    return f;
}
__device__ __forceinline__ unsigned int f2bf(float f) {
    unsigned int x;
    __builtin_memcpy(&x, &f, 4);
    unsigned int r = x + 0x7FFFu + ((x >> 16) & 1u);
    return r >> 16;
}

// ======================= CSR build =======================

__global__ __launch_bounds__(256) void count_kernel(const int* __restrict__ dst,
                                                    int* __restrict__ cnt) {
    int e = blockIdx.x * 256 + threadIdx.x;
    if (e < NE) atomicAdd(&cnt[dst[e]], 1);
}

__global__ __launch_bounds__(256) void scan1_kernel(const int* __restrict__ cnt,
                                                    int* __restrict__ part,
                                                    int* __restrict__ bsum) {
    __shared__ int ts[256];
    int t = threadIdx.x;
    int base = blockIdx.x * SCAN_BS + t * 4;
    int c0 = (base     < NN) ? cnt[base]     : 0;
    int c1 = (base + 1 < NN) ? cnt[base + 1] : 0;
    int c2 = (base + 2 < NN) ? cnt[base + 2] : 0;
    int c3 = (base + 3 < NN) ? cnt[base + 3] : 0;
    int sum = c0 + c1 + c2 + c3;
    ts[t] = sum;
    __syncthreads();
    for (int off = 1; off < 256; off <<= 1) {
        int u = (t >= off) ? ts[t - off] : 0;
        __syncthreads();
        ts[t] += u;
        __syncthreads();
    }
    int excl = ts[t] - sum;
    if (t == 255) bsum[blockIdx.x] = ts[255];
    if (base     < NN) part[base]     = excl;
    if (base + 1 < NN) part[base + 1] = excl + c0;
    if (base + 2 < NN) part[base + 2] = excl + c0 + c1;
    if (base + 3 < NN) part[base + 3] = excl + c0 + c1 + c2;
}

__global__ void scan2_kernel(int* __restrict__ bsum) {
    if (threadIdx.x == 0 && blockIdx.x == 0) {
        int acc = 0;
        for (int i = 0; i < NBLK; i++) { int v = bsum[i]; bsum[i] = acc; acc += v; }
    }
}

__global__ __launch_bounds__(256) void scan3_kernel(int* __restrict__ part,
                                                    const int* __restrict__ bsum) {
    int i = blockIdx.x * 256 + threadIdx.x;
    if (i < NN) part[i] += bsum[i / SCAN_BS];
    if (i == 0) part[NN] = NE;
}

__global__ __launch_bounds__(256) void copy_kernel(const int* __restrict__ row,
                                                   int* __restrict__ cursor) {
    int i = blockIdx.x * 256 + threadIdx.x;
    if (i < NN) cursor[i] = row[i];
}

__global__ __launch_bounds__(256) void fill_kernel(const int* __restrict__ src,
                                                   const int* __restrict__ dst,
                                                   const float* __restrict__ w,
                                                   int* __restrict__ cursor,
                                                   int* __restrict__ csrc,
                                                   float* __restrict__ csrw) {
    int e = blockIdx.x * 256 + threadIdx.x;
    if (e >= NE) return;
    int d = dst[e];
    int pos = atomicAdd(&cursor[d], 1);
    csrc[pos] = src[e];
    csrw[pos] = w[e];
}

// ======================= weight prep =======================
__global__ __launch_bounds__(256) void wprep_kernel(const float* __restrict__ Ws,
                                                    const float* __restrict__ Wn,
                                                    unsigned short* __restrict__ wcat) {
    int idx = blockIdx.x * 256 + threadIdx.x;   // 128*256 = 32768
    if (idx >= 128 * 256) return;
    int n = idx >> 8, k = idx & 255;
    float v = (k < 128) ? Ws[n * 128 + k] : Wn[n * 128 + (k - 128)];
    wcat[idx] = (unsigned short)f2bf(v);
}

// ======================= gathers =======================
// 2 nodes per 256-block; 128 threads per node, thread j owns feature j.
__global__ __launch_bounds__(256) void gather_f32(const float* __restrict__ h,
                                                  const int* __restrict__ row,
                                                  const int* __restrict__ csrc,
                                                  const float* __restrict__ csrw,
                                                  unsigned short* __restrict__ sbf) {
    int t = threadIdx.x;
    int j = t & 127;
    int n = blockIdx.x * 2 + (t >> 7);
    int beg = row[n], end = row[n + 1];
    float acc = 0.0f;
    int e = beg;
    for (; e + 1 < end; e += 2) {
        int s0 = csrc[e], s1 = csrc[e + 1];
        float w0 = csrw[e], w1 = csrw[e + 1];
        acc += w0 * h[(size_t)s0 * F + j] + w1 * h[(size_t)s1 * F + j];
    }
    if (e < end) acc += csrw[e] * h[(size_t)csrc[e] * F + j];
    float invd = 1.0f / fmaxf((float)(end - beg), 1.0f);
    sbf[(size_t)n * F + j] = (unsigned short)f2bf(acc * invd);
}

__global__ __launch_bounds__(256) void gather_bf16(const unsigned short* __restrict__ h,
                                                   const int* __restrict__ row,
                                                   const int* __restrict__ csrc,
                                                   const float* __restrict__ csrw,
                                                   unsigned short* __restrict__ sbf) {
    int t = threadIdx.x;
    int j = t & 127;
    int n = blockIdx.x * 2 + (t >> 7);
    int beg = row[n], end = row[n + 1];
    float acc = 0.0f;
    int e = beg;
    for (; e + 1 < end; e += 2) {
        int s0 = csrc[e], s1 = csrc[e + 1];
        float w0 = csrw[e], w1 = csrw[e + 1];
        acc += w0 * bf2f(h[(size_t)s0 * F + j]) + w1 * bf2f(h[(size_t)s1 * F + j]);
    }
    if (e < end) acc += csrw[e] * bf2f(h[(size_t)csrc[e] * F + j]);
    float invd = 1.0f / fmaxf((float)(end - beg), 1.0f);
    sbf[(size_t)n * F + j] = (unsigned short)f2bf(acc * invd);
}

// ======================= MFMA GEMM =======================
// Block: 256 threads = 4 waves, 128-row M-tile, all 128 cols.
// Wave w computes rows [w*32, w*32+32) as 2x8 grid of 16x16 tiles.
// K=256: first 128 from self source, last 128 from s_bf.
#define APAD 40   // LDS row stride in bf16 (32 data + 8 pad)

__global__ __launch_bounds__(256) void mfma_gemm(
    const float* __restrict__ self_f32,          // layer1 self input (or null)
    const unsigned short* __restrict__ self_bf,  // layer2 self input (or null)
    const unsigned short* __restrict__ sbf,      // bf16 [NN,F] normalized neigh
    const unsigned short* __restrict__ wcat,     // bf16 [128][256]
    const float* __restrict__ bias,              // f32 [128]
    unsigned short* __restrict__ out_bf,         // layer1 out (relu+bf16) or null
    float* __restrict__ out_f32)                 // layer2 out (f32) or null
{
    __shared__ unsigned short At[128][APAD];

    int t = threadIdx.x;
    int l = t & 63;
    int w = t >> 6;
    int base = blockIdx.x * 128;
    int lane16 = l & 15;
    int quad = l >> 4;

    float4v acc0[8], acc1[8];
#pragma unroll
    for (int ct = 0; ct < 8; ct++) {
        acc0[ct] = (float4v){0.f, 0.f, 0.f, 0.f};
        acc1[ct] = (float4v){0.f, 0.f, 0.f, 0.f};
    }

    for (int half = 0; half < 2; half++) {
        for (int kk = 0; kk < 4; kk++) {
            int k0 = kk * 32;
            __syncthreads();   // previous iter's reads complete
            if (half == 0 && self_f32) {
                // stage f32 -> bf16: 128 rows x 32 k = 1024 float4 chunks
                for (int idx = t; idx < 1024; idx += 256) {
                    int m = idx >> 3, q = idx & 7;
                    int row = base + m;
                    float4 v = make_float4(0.f, 0.f, 0.f, 0.f);
                    if (row < NN) v = *(const float4*)(self_f32 + (size_t)row * F + k0 + q * 4);
                    unsigned int p0 = f2bf(v.x) | (f2bf(v.y) << 16);
                    unsigned int p1 = f2bf(v.z) | (f2bf(v.w) << 16);
                    uint2 pk; pk.x = p0; pk.y = p1;
                    *(uint2*)&At[m][q * 4] = pk;
                }
            } else {
                const unsigned short* srcb = (half == 0) ? self_bf : sbf;
                // stage bf16 copy: 128 rows x 32 k = 512 16B chunks
                for (int idx = t; idx < 512; idx += 256) {
                    int m = idx >> 2, q = idx & 3;
                    int row = base + m;
                    uint4 v = make_uint4(0u, 0u, 0u, 0u);
                    if (row < NN) v = *(const uint4*)(srcb + (size_t)row * F + k0 + q * 8);
                    *(uint4*)&At[m][q * 8] = v;
                }
            }
            __syncthreads();

            short8 a0 = *(const short8*)&At[w * 32 + lane16][quad * 8];
            short8 a1 = *(const short8*)&At[w * 32 + 16 + lane16][quad * 8];
#pragma unroll
            for (int ct = 0; ct < 8; ct++) {
                short8 b = *(const short8*)(wcat +
                    (size_t)(ct * 16 + lane16) * 256 + half * 128 + k0 + quad * 8);
                acc0[ct] = __builtin_amdgcn_mfma_f32_16x16x32_bf16(a0, b, acc0[ct], 0, 0, 0);
                acc1[ct] = __builtin_amdgcn_mfma_f32_16x16x32_bf16(a1, b, acc1[ct], 0, 0, 0);
            }
        }
    }

    // epilogue: C/D layout col=l&15, row=quad*4+r
    int rowb0 = base + w * 32 + quad * 4;
    int rowb1 = rowb0 + 16;
#pragma unroll
    for (int ct = 0; ct < 8; ct++) {
        int col = ct * 16 + lane16;
        float bc = bias[col];
#pragma unroll
        for (int r = 0; r < 4; r++) {
            int g0 = rowb0 + r, g1 = rowb1 + r;
            float v0 = acc0[ct][r] + bc;
            float v1 = acc1[ct][r] + bc;
            if (out_bf) {
                v0 = fmaxf(v0, 0.0f);
                v1 = fmaxf(v1, 0.0f);
                if (g0 < NN) out_bf[(size_t)g0 * F + col] = (unsigned short)f2bf(v0);
                if (g1 < NN) out_bf[(size_t)g1 * F + col] = (unsigned short)f2bf(v1);
            } else {
                if (g0 < NN) out_f32[(size_t)g0 * F + col] = v0;
                if (g1 < NN) out_f32[(size_t)g1 * F + col] = v1;
            }
        }
    }
}

// ======================= fallback (round-4 f32 path) =======================

__global__ __launch_bounds__(256) void scatter_kernel(const float* __restrict__ h,
                                                      const float* __restrict__ w,
                                                      const int* __restrict__ src,
                                                      const int* __restrict__ dst,
                                                      float* __restrict__ s,
                                                      float* __restrict__ deg,
                                                      int add_deg) {
    int e = blockIdx.x * 4 + (threadIdx.x >> 6);
    int lane = threadIdx.x & 63;
    int sn = src[e];
    int dn = dst[e];
    float wf = w[e];
    float2 p = *(const float2*)(h + (size_t)sn * F + lane * 2);
    float* sp = s + (size_t)dn * F + lane * 2;
    unsafeAtomicAdd(sp,     wf * p.x);
    unsafeAtomicAdd(sp + 1, wf * p.y);
    if (add_deg && lane == 0) unsafeAtomicAdd(&deg[dn], 1.0f);
}

__global__ __launch_bounds__(256) void sage_gemm(const float* h,
                                                 const float* __restrict__ s,
                                                 const float* deg,
                                                 const float* __restrict__ Ws,
                                                 const float* __restrict__ bias,
                                                 const float* __restrict__ Wn,
                                                 float* out,
                                                 int relu) {
    __shared__ float xs[16][F];
    __shared__ float invd[16];
    int t = threadIdx.x;
    int j = t & 127;
    int g = t >> 7;
    int base = blockIdx.x * 16;
    for (int idx = t; idx < 16 * 32; idx += 256) {
        int n = idx >> 5, kq = idx & 31;
        *(float4*)&xs[n][kq * 4] = *(const float4*)(h + (size_t)(base + n) * F + kq * 4);
    }
    if (t < 16) invd[t] = deg ? 1.0f / fmaxf(deg[base + t], 1.0f) : 1.0f;
    __syncthreads();
    float acc[8];
#pragma unroll
    for (int i = 0; i < 8; i++) acc[i] = 0.0f;
    for (int kc = 0; kc < F; kc += 4) {
        float4 wv = *(const float4*)(Ws + j * F + kc);
#pragma unroll
        for (int i = 0; i < 8; i++) {
            const float* xr = &xs[g * 8 + i][kc];
            acc[i] += xr[0] * wv.x + xr[1] * wv.y + xr[2] * wv.z + xr[3] * wv.w;
        }
    }
    __syncthreads();
    for (int idx = t; idx < 16 * 32; idx += 256) {
        int n = idx >> 5, kq = idx & 31;
        float4 sv = *(const float4*)(s + (size_t)(base + n) * F + kq * 4);
        float iv = invd[n];
        xs[n][kq * 4]     = sv.x * iv;
        xs[n][kq * 4 + 1] = sv.y * iv;
        xs[n][kq * 4 + 2] = sv.z * iv;
        xs[n][kq * 4 + 3] = sv.w * iv;
    }
    __syncthreads();
    for (int kc = 0; kc < F; kc += 4) {
        float4 wv = *(const float4*)(Wn + j * F + kc);
#pragma unroll
        for (int i = 0; i < 8; i++) {
            const float* xr = &xs[g * 8 + i][kc];
            acc[i] += xr[0] * wv.x + xr[1] * wv.y + xr[2] * wv.z + xr[3] * wv.w;
        }
    }
    float bj = bias[j];
#pragma unroll
    for (int i = 0; i < 8; i++) {
        int n = base + g * 8 + i;
        float v = acc[i] + bj;
        if (relu) v = fmaxf(v, 0.0f);
        out[(size_t)n * F + j] = v;
    }
}

extern "C" void kernel_launch(void* const* d_in, const int* in_sizes, int n_in,
                              void* d_out, int out_size, void* d_ws, size_t ws_size,
                              hipStream_t stream) {
    const float* in_feat = (const float*)d_in[0];
    const float* weights = (const float*)d_in[1];
    const int* src = (const int*)d_in[2];
    const int* dst = (const int*)d_in[3];
    const float* Ws1 = (const float*)d_in[4];
    const float* b1  = (const float*)d_in[5];
    const float* Wn1 = (const float*)d_in[6];
    const float* Ws2 = (const float*)d_in[7];
    const float* b2  = (const float*)d_in[8];
    const float* Wn2 = (const float*)d_in[9];
    float* out = (float*)d_out;

    if (ws_size >= WS_NEED) {
        int* cnt    = (int*)((char*)d_ws + CNT_OFF);
        int* row    = (int*)((char*)d_ws + ROW_OFF);
        int* bsum   = (int*)((char*)d_ws + BSUM_OFF);
        int* csrc   = (int*)((char*)d_ws + CSRC_OFF);
        float* csrw = (float*)((char*)d_ws + CSRW_OFF);
        unsigned short* wcat1 = (unsigned short*)((char*)d_ws + WCAT1_OFF);
        unsigned short* wcat2 = (unsigned short*)((char*)d_ws + WCAT2_OFF);
        unsigned short* sbf   = (unsigned short*)((char*)d_ws + SBF_OFF);
        unsigned short* h1bf  = (unsigned short*)((char*)d_ws + H1BF_OFF);

        hipMemsetAsync(cnt, 0, 400000, stream);
        count_kernel<<<(NE + 255) / 256, 256, 0, stream>>>(dst, cnt);
        scan1_kernel<<<NBLK, 256, 0, stream>>>(cnt, row, bsum);
        scan2_kernel<<<1, 64, 0, stream>>>(bsum);
        scan3_kernel<<<(NN + 255) / 256, 256, 0, stream>>>(row, bsum);
        copy_kernel<<<(NN + 255) / 256, 256, 0, stream>>>(row, cnt);
        fill_kernel<<<(NE + 255) / 256, 256, 0, stream>>>(src, dst, weights, cnt, csrc, csrw);
        wprep_kernel<<<128, 256, 0, stream>>>(Ws1, Wn1, wcat1);
        wprep_kernel<<<128, 256, 0, stream>>>(Ws2, Wn2, wcat2);

        // layer 1
        gather_f32<<<NN / 2, 256, 0, stream>>>(in_feat, row, csrc, csrw, sbf);
        mfma_gemm<<<(NN + 127) / 128, 256, 0, stream>>>(
            in_feat, nullptr, sbf, wcat1, b1, h1bf, nullptr);
        // layer 2
        gather_bf16<<<NN / 2, 256, 0, stream>>>(h1bf, row, csrc, csrw, sbf);
        mfma_gemm<<<(NN + 127) / 128, 256, 0, stream>>>(
            nullptr, h1bf, sbf, wcat2, b2, nullptr, out);
    } else {
        float* deg = (float*)d_ws;
        float* s   = (float*)((char*)d_ws + FB_S_OFF);
        hipMemsetAsync(d_ws, 0, FB_S_OFF + (size_t)NN * F * 4, stream);
        scatter_kernel<<<NE / 4, 256, 0, stream>>>(in_feat, weights, src, dst, s, deg, 1);
        sage_gemm<<<NN / 16, 256, 0, stream>>>(in_feat, s, deg, Ws1, b1, Wn1, out, 1);
        hipMemsetAsync(s, 0, (size_t)NN * F * 4, stream);
        scatter_kernel<<<NE / 4, 256, 0, stream>>>(out, weights, src, dst, s, deg, 0);
        sage_gemm<<<NN / 16, 256, 0, stream>>>(out, s, deg, Ws2, b2, Wn2, out, 0);
    }
}

// Round 6
// 561.703 us; speedup vs baseline: 5.7284x; 1.3673x over previous
//
#include <hip/hip_runtime.h>

// GraphSAGE 2-layer, N=100000, E=1600000, F=128. Inputs f32; src/dst int32.
//
// Pipeline (CSR path, ws >= ~65 MB proven):
//   memset(cnt); count; scan1/2/3 -> row[NN+1]; cursor=row; fill CSR
//   wprep:  Wcat_l[n][0..255] bf16 = Ws_l[n][:] ‖ Wn_l[n][:]
//   conv:   infbf = bf16(in_feat)            [lives in H1BF slot]
//   gather1: sbf[n] = bf16((1/deg) sum w_e*infbf[src_e])   (packed uint loads)
//   gemm1:  h1bf = bf16(relu(...))  IN-PLACE over infbf (disjoint 128-row
//           tiles; all reads of a tile precede its epilogue writes)
//   gather2: sbf from h1bf
//   gemm2:  d_out f32
//
// MFMA 16x16x32_bf16 (m89-verified): A lane l: A[m=l&15][k=(l>>4)*8+j];
// B lane l: B[k=(l>>4)*8+j][n=l&15] == W[n][k] row-major; C/D: col=l&15,
// row=(l>>4)*4+r.

#define NN 100000
#define NE 1600000
#define F 128

#define SCAN_BS 1024
#define NBLK ((NN + SCAN_BS - 1) / SCAN_BS)   // 98

// ---- ws layout (bytes) ----
static const size_t CNT_OFF   = 0;          // int[NN] counters -> fill cursor
static const size_t ROW_OFF   = 400000;     // int[NN+1]
static const size_t BSUM_OFF  = 800016;     // int[NBLK]
static const size_t CSRC_OFF  = 804112;     // int[NE]
static const size_t CSRW_OFF  = 7204112;    // f32[NE]
static const size_t WCAT1_OFF = 13604112;   // bf16[128*256]
static const size_t WCAT2_OFF = 13669648;   // bf16[128*256]
static const size_t SBF_OFF   = 13735184;   // bf16[NN*F]
static const size_t H1BF_OFF  = 39335184;   // bf16[NN*F]  (infbf then h1bf)
static const size_t WS_NEED   = 64935184;

// ---- fallback layout ----
static const size_t FB_S_OFF = 524288;      // deg f32[NN] @0, s f32[NN*F]

typedef __attribute__((ext_vector_type(8))) short short8;
typedef __attribute__((ext_vector_type(4))) float float4v;

__device__ __forceinline__ float bf2f(unsigned int u16) {
    unsigned int x = u16 << 16;
    float f;
    __builtin_memcpy(&f, &x, 4);
    return f;
}
__device__ __forceinline__ unsigned int f2bf(float f) {
    unsigned int x;
    __builtin_memcpy(&x, &f, 4);
    unsigned int r = x + 0x7FFFu + ((x >> 16) & 1u);
    return r >> 16;
}

// ======================= CSR build =======================

__global__ __launch_bounds__(256) void count_kernel(const int* __restrict__ dst,
                                                    int* __restrict__ cnt) {
    int e = blockIdx.x * 256 + threadIdx.x;
    if (e < NE) atomicAdd(&cnt[dst[e]], 1);
}

__global__ __launch_bounds__(256) void scan1_kernel(const int* __restrict__ cnt,
                                                    int* __restrict__ part,
                                                    int* __restrict__ bsum) {
    __shared__ int ts[256];
    int t = threadIdx.x;
    int base = blockIdx.x * SCAN_BS + t * 4;
    int c0 = (base     < NN) ? cnt[base]     : 0;
    int c1 = (base + 1 < NN) ? cnt[base + 1] : 0;
    int c2 = (base + 2 < NN) ? cnt[base + 2] : 0;
    int c3 = (base + 3 < NN) ? cnt[base + 3] : 0;
    int sum = c0 + c1 + c2 + c3;
    ts[t] = sum;
    __syncthreads();
    for (int off = 1; off < 256; off <<= 1) {
        int u = (t >= off) ? ts[t - off] : 0;
        __syncthreads();
        ts[t] += u;
        __syncthreads();
    }
    int excl = ts[t] - sum;
    if (t == 255) bsum[blockIdx.x] = ts[255];
    if (base     < NN) part[base]     = excl;
    if (base + 1 < NN) part[base + 1] = excl + c0;
    if (base + 2 < NN) part[base + 2] = excl + c0 + c1;
    if (base + 3 < NN) part[base + 3] = excl + c0 + c1 + c2;
}

__global__ void scan2_kernel(int* __restrict__ bsum) {
    if (threadIdx.x == 0 && blockIdx.x == 0) {
        int acc = 0;
        for (int i = 0; i < NBLK; i++) { int v = bsum[i]; bsum[i] = acc; acc += v; }
    }
}

__global__ __launch_bounds__(256) void scan3_kernel(int* __restrict__ part,
                                                    const int* __restrict__ bsum) {
    int i = blockIdx.x * 256 + threadIdx.x;
    if (i < NN) part[i] += bsum[i / SCAN_BS];
    if (i == 0) part[NN] = NE;
}

__global__ __launch_bounds__(256) void copy_kernel(const int* __restrict__ row,
                                                   int* __restrict__ cursor) {
    int i = blockIdx.x * 256 + threadIdx.x;
    if (i < NN) cursor[i] = row[i];
}

__global__ __launch_bounds__(256) void fill_kernel(const int* __restrict__ src,
                                                   const int* __restrict__ dst,
                                                   const float* __restrict__ w,
                                                   int* __restrict__ cursor,
                                                   int* __restrict__ csrc,
                                                   float* __restrict__ csrw) {
    int e = blockIdx.x * 256 + threadIdx.x;
    if (e >= NE) return;
    int d = dst[e];
    int pos = atomicAdd(&cursor[d], 1);
    csrc[pos] = src[e];
    csrw[pos] = w[e];
}

// ======================= weight / input prep =======================

__global__ __launch_bounds__(256) void wprep_kernel(const float* __restrict__ Ws,
                                                    const float* __restrict__ Wn,
                                                    unsigned short* __restrict__ wcat) {
    int idx = blockIdx.x * 256 + threadIdx.x;   // 32768
    if (idx >= 128 * 256) return;
    int n = idx >> 8, k = idx & 255;
    float v = (k < 128) ? Ws[n * 128 + k] : Wn[n * 128 + (k - 128)];
    wcat[idx] = (unsigned short)f2bf(v);
}

// f32 -> bf16, 8 elems/thread (NN*F = 12.8M, divisible by 8*256)
__global__ __launch_bounds__(256) void conv_bf16(const float* __restrict__ in,
                                                 unsigned short* __restrict__ outbf) {
    size_t base = ((size_t)blockIdx.x * 256 + threadIdx.x) * 8;
    float4 a = *(const float4*)(in + base);
    float4 b = *(const float4*)(in + base + 4);
    uint4 p;
    p.x = f2bf(a.x) | (f2bf(a.y) << 16);
    p.y = f2bf(a.z) | (f2bf(a.w) << 16);
    p.z = f2bf(b.x) | (f2bf(b.y) << 16);
    p.w = f2bf(b.z) | (f2bf(b.w) << 16);
    *(uint4*)(outbf + base) = p;
}

// ======================= gather (packed bf16) =======================
// 4 nodes per 256-block; 64 threads/node; thread owns features 2l, 2l+1
// (one uint = 2 bf16). Wave reads one contiguous 256 B row segment per edge.
__global__ __launch_bounds__(256) void gather_packed(const unsigned short* __restrict__ h,
                                                     const int* __restrict__ row,
                                                     const int* __restrict__ csrc,
                                                     const float* __restrict__ csrw,
                                                     unsigned short* __restrict__ sbf) {
    int t = threadIdx.x;
    int lane = t & 63;
    int n = blockIdx.x * 4 + (t >> 6);           // NN divisible by 4
    int beg = __builtin_amdgcn_readfirstlane(row[n]);
    int end = __builtin_amdgcn_readfirstlane(row[n + 1]);
    const unsigned int* hp = (const unsigned int*)h;   // row stride 64 uints

    float ax = 0.0f, ay = 0.0f;
    int e = beg;
    for (; e + 3 < end; e += 4) {
        int s0 = csrc[e], s1 = csrc[e + 1], s2 = csrc[e + 2], s3 = csrc[e + 3];
        float w0 = csrw[e], w1 = csrw[e + 1], w2 = csrw[e + 2], w3 = csrw[e + 3];
        unsigned int p0 = hp[(size_t)s0 * 64 + lane];
        unsigned int p1 = hp[(size_t)s1 * 64 + lane];
        unsigned int p2 = hp[(size_t)s2 * 64 + lane];
        unsigned int p3 = hp[(size_t)s3 * 64 + lane];
        ax += w0 * bf2f(p0 & 0xFFFFu) + w1 * bf2f(p1 & 0xFFFFu)
            + w2 * bf2f(p2 & 0xFFFFu) + w3 * bf2f(p3 & 0xFFFFu);
        ay += w0 * bf2f(p0 >> 16) + w1 * bf2f(p1 >> 16)
            + w2 * bf2f(p2 >> 16) + w3 * bf2f(p3 >> 16);
    }
    for (; e < end; e++) {
        int s0 = csrc[e];
        float w0 = csrw[e];
        unsigned int p0 = hp[(size_t)s0 * 64 + lane];
        ax += w0 * bf2f(p0 & 0xFFFFu);
        ay += w0 * bf2f(p0 >> 16);
    }
    float invd = 1.0f / fmaxf((float)(end - beg), 1.0f);
    unsigned int outp = f2bf(ax * invd) | (f2bf(ay * invd) << 16);
    ((unsigned int*)sbf)[(size_t)n * 64 + lane] = outp;
}

// ======================= MFMA GEMM =======================
// 256 threads = 4 waves; 128-row M-tile x 128 cols; wave w: rows [w*32,w*32+32)
// as 2x8 grid of 16x16 tiles. K=256 = self(128) ‖ neigh(128).
// NOTE: self_bf/out_bf deliberately NOT __restrict__ — gemm1 runs in-place
// (out_bf == self_bf); per-block reads of its rows all precede its writes.
#define APAD 40   // LDS row stride in bf16 (32 data + 8 pad)

__global__ __launch_bounds__(256) void mfma_gemm(
    const unsigned short* self_bf,               // bf16 [NN,F]
    const unsigned short* __restrict__ sbf,      // bf16 [NN,F] normalized neigh
    const unsigned short* __restrict__ wcat,     // bf16 [128][256]
    const float* __restrict__ bias,              // f32 [128]
    unsigned short* out_bf,                      // layer1: relu+bf16 (or null)
    float* __restrict__ out_f32)                 // layer2: f32 (or null)
{
    __shared__ unsigned short At[128][APAD];

    int t = threadIdx.x;
    int l = t & 63;
    int w = t >> 6;
    int base = blockIdx.x * 128;
    int lane16 = l & 15;
    int quad = l >> 4;

    float4v acc0[8], acc1[8];
#pragma unroll
    for (int ct = 0; ct < 8; ct++) {
        acc0[ct] = (float4v){0.f, 0.f, 0.f, 0.f};
        acc1[ct] = (float4v){0.f, 0.f, 0.f, 0.f};
    }

    for (int half = 0; half < 2; half++) {
        const unsigned short* srcb = (half == 0) ? self_bf : sbf;
        for (int kk = 0; kk < 4; kk++) {
            int k0 = kk * 32;
            __syncthreads();
            for (int idx = t; idx < 512; idx += 256) {
                int m = idx >> 2, q = idx & 3;
                int row = base + m;
                uint4 v = make_uint4(0u, 0u, 0u, 0u);
                if (row < NN) v = *(const uint4*)(srcb + (size_t)row * F + k0 + q * 8);
                *(uint4*)&At[m][q * 8] = v;
            }
            __syncthreads();

            short8 a0 = *(const short8*)&At[w * 32 + lane16][quad * 8];
            short8 a1 = *(const short8*)&At[w * 32 + 16 + lane16][quad * 8];
#pragma unroll
            for (int ct = 0; ct < 8; ct++) {
                short8 b = *(const short8*)(wcat +
                    (size_t)(ct * 16 + lane16) * 256 + half * 128 + k0 + quad * 8);
                acc0[ct] = __builtin_amdgcn_mfma_f32_16x16x32_bf16(a0, b, acc0[ct], 0, 0, 0);
                acc1[ct] = __builtin_amdgcn_mfma_f32_16x16x32_bf16(a1, b, acc1[ct], 0, 0, 0);
            }
        }
    }

    int rowb0 = base + w * 32 + quad * 4;
    int rowb1 = rowb0 + 16;
#pragma unroll
    for (int ct = 0; ct < 8; ct++) {
        int col = ct * 16 + lane16;
        float bc = bias[col];
#pragma unroll
        for (int r = 0; r < 4; r++) {
            int g0 = rowb0 + r, g1 = rowb1 + r;
            float v0 = acc0[ct][r] + bc;
            float v1 = acc1[ct][r] + bc;
            if (out_bf) {
                v0 = fmaxf(v0, 0.0f);
                v1 = fmaxf(v1, 0.0f);
                if (g0 < NN) out_bf[(size_t)g0 * F + col] = (unsigned short)f2bf(v0);
                if (g1 < NN) out_bf[(size_t)g1 * F + col] = (unsigned short)f2bf(v1);
            } else {
                if (g0 < NN) out_f32[(size_t)g0 * F + col] = v0;
                if (g1 < NN) out_f32[(size_t)g1 * F + col] = v1;
            }
        }
    }
}

// ======================= fallback (f32 atomic path) =======================

__global__ __launch_bounds__(256) void scatter_kernel(const float* __restrict__ h,
                                                      const float* __restrict__ w,
                                                      const int* __restrict__ src,
                                                      const int* __restrict__ dst,
                                                      float* __restrict__ s,
                                                      float* __restrict__ deg,
                                                      int add_deg) {
    int e = blockIdx.x * 4 + (threadIdx.x >> 6);
    int lane = threadIdx.x & 63;
    int sn = src[e];
    int dn = dst[e];
    float wf = w[e];
    float2 p = *(const float2*)(h + (size_t)sn * F + lane * 2);
    float* sp = s + (size_t)dn * F + lane * 2;
    unsafeAtomicAdd(sp,     wf * p.x);
    unsafeAtomicAdd(sp + 1, wf * p.y);
    if (add_deg && lane == 0) unsafeAtomicAdd(&deg[dn], 1.0f);
}

__global__ __launch_bounds__(256) void sage_gemm(const float* h,
                                                 const float* __restrict__ s,
                                                 const float* deg,
                                                 const float* __restrict__ Ws,
                                                 const float* __restrict__ bias,
                                                 const float* __restrict__ Wn,
                                                 float* out,
                                                 int relu) {
    __shared__ float xs[16][F];
    __shared__ float invd[16];
    int t = threadIdx.x;
    int j = t & 127;
    int g = t >> 7;
    int base = blockIdx.x * 16;
    for (int idx = t; idx < 16 * 32; idx += 256) {
        int n = idx >> 5, kq = idx & 31;
        *(float4*)&xs[n][kq * 4] = *(const float4*)(h + (size_t)(base + n) * F + kq * 4);
    }
    if (t < 16) invd[t] = deg ? 1.0f / fmaxf(deg[base + t], 1.0f) : 1.0f;
    __syncthreads();
    float acc[8];
#pragma unroll
    for (int i = 0; i < 8; i++) acc[i] = 0.0f;
    for (int kc = 0; kc < F; kc += 4) {
        float4 wv = *(const float4*)(Ws + j * F + kc);
#pragma unroll
        for (int i = 0; i < 8; i++) {
            const float* xr = &xs[g * 8 + i][kc];
            acc[i] += xr[0] * wv.x + xr[1] * wv.y + xr[2] * wv.z + xr[3] * wv.w;
        }
    }
    __syncthreads();
    for (int idx = t; idx < 16 * 32; idx += 256) {
        int n = idx >> 5, kq = idx & 31;
        float4 sv = *(const float4*)(s + (size_t)(base + n) * F + kq * 4);
        float iv = invd[n];
        xs[n][kq * 4]     = sv.x * iv;
        xs[n][kq * 4 + 1] = sv.y * iv;
        xs[n][kq * 4 + 2] = sv.z * iv;
        xs[n][kq * 4 + 3] = sv.w * iv;
    }
    __syncthreads();
    for (int kc = 0; kc < F; kc += 4) {
        float4 wv = *(const float4*)(Wn + j * F + kc);
#pragma unroll
        for (int i = 0; i < 8; i++) {
            const float* xr = &xs[g * 8 + i][kc];
            acc[i] += xr[0] * wv.x + xr[1] * wv.y + xr[2] * wv.z + xr[3] * wv.w;
        }
    }
    float bj = bias[j];
#pragma unroll
    for (int i = 0; i < 8; i++) {
        int n = base + g * 8 + i;
        float v = acc[i] + bj;
        if (relu) v = fmaxf(v, 0.0f);
        out[(size_t)n * F + j] = v;
    }
}

extern "C" void kernel_launch(void* const* d_in, const int* in_sizes, int n_in,
                              void* d_out, int out_size, void* d_ws, size_t ws_size,
                              hipStream_t stream) {
    const float* in_feat = (const float*)d_in[0];
    const float* weights = (const float*)d_in[1];
    const int* src = (const int*)d_in[2];
    const int* dst = (const int*)d_in[3];
    const float* Ws1 = (const float*)d_in[4];
    const float* b1  = (const float*)d_in[5];
    const float* Wn1 = (const float*)d_in[6];
    const float* Ws2 = (const float*)d_in[7];
    const float* b2  = (const float*)d_in[8];
    const float* Wn2 = (const float*)d_in[9];
    float* out = (float*)d_out;

    if (ws_size >= WS_NEED) {
        int* cnt    = (int*)((char*)d_ws + CNT_OFF);
        int* row    = (int*)((char*)d_ws + ROW_OFF);
        int* bsum   = (int*)((char*)d_ws + BSUM_OFF);
        int* csrc   = (int*)((char*)d_ws + CSRC_OFF);
        float* csrw = (float*)((char*)d_ws + CSRW_OFF);
        unsigned short* wcat1 = (unsigned short*)((char*)d_ws + WCAT1_OFF);
        unsigned short* wcat2 = (unsigned short*)((char*)d_ws + WCAT2_OFF);
        unsigned short* sbf   = (unsigned short*)((char*)d_ws + SBF_OFF);
        unsigned short* hbf   = (unsigned short*)((char*)d_ws + H1BF_OFF); // infbf -> h1bf

        hipMemsetAsync(cnt, 0, 400000, stream);
        count_kernel<<<(NE + 255) / 256, 256, 0, stream>>>(dst, cnt);
        scan1_kernel<<<NBLK, 256, 0, stream>>>(cnt, row, bsum);
        scan2_kernel<<<1, 64, 0, stream>>>(bsum);
        scan3_kernel<<<(NN + 255) / 256, 256, 0, stream>>>(row, bsum);
        copy_kernel<<<(NN + 255) / 256, 256, 0, stream>>>(row, cnt);
        fill_kernel<<<(NE + 255) / 256, 256, 0, stream>>>(src, dst, weights, cnt, csrc, csrw);
        wprep_kernel<<<128, 256, 0, stream>>>(Ws1, Wn1, wcat1);
        wprep_kernel<<<128, 256, 0, stream>>>(Ws2, Wn2, wcat2);
        conv_bf16<<<6250, 256, 0, stream>>>(in_feat, hbf);

        // layer 1 (gemm1 in-place over hbf: infbf -> h1bf)
        gather_packed<<<NN / 4, 256, 0, stream>>>(hbf, row, csrc, csrw, sbf);
        mfma_gemm<<<(NN + 127) / 128, 256, 0, stream>>>(hbf, sbf, wcat1, b1, hbf, nullptr);
        // layer 2
        gather_packed<<<NN / 4, 256, 0, stream>>>(hbf, row, csrc, csrw, sbf);
        mfma_gemm<<<(NN + 127) / 128, 256, 0, stream>>>(hbf, sbf, wcat2, b2, nullptr, out);
    } else {
        float* deg = (float*)d_ws;
        float* s   = (float*)((char*)d_ws + FB_S_OFF);
        hipMemsetAsync(d_ws, 0, FB_S_OFF + (size_t)NN * F * 4, stream);
        scatter_kernel<<<NE / 4, 256, 0, stream>>>(in_feat, weights, src, dst, s, deg, 1);
        sage_gemm<<<NN / 16, 256, 0, stream>>>(in_feat, s, deg, Ws1, b1, Wn1, out, 1);
        hipMemsetAsync(s, 0, (size_t)NN * F * 4, stream);
        scatter_kernel<<<NE / 4, 256, 0, stream>>>(out, weights, src, dst, s, deg, 0);
        sage_gemm<<<NN / 16, 256, 0, stream>>>(out, s, deg, Ws2, b2, Wn2, out, 0);
    }
}